// Round 3
// baseline (1300.516 us; speedup 1.0000x reference)
//
#include <hip/hip_runtime.h>
#include <hip/hip_bf16.h>
#include <stdint.h>

// CachedOPTAttention: B=4, T=1024, D=2048, H=32, HD=64, causal, idx=0.
// FP32 buffers; bf16-class error budget -> bf16 MFMA math inside.
//
// R5: GEMMs ported to the 256x256 8-phase deep-pipeline template (BK=64,
// 8 waves 2Mx4N, 128KiB dbuf LDS, quarter-tile global_load_lds staging,
// counted vmcnt(4)/vmcnt(2) - never 0 in the main loop, setprio around MFMA,
// row&7 chunk-XOR LDS swizzle via pre-swizzled global source).
//
// vmcnt ledger (per wave, 8 loads/tile, issue order Bq01,Bq23,Aq02,Aq13):
//   tile-entry: [Aq1,Aq3(t)] in flight (2)
//   p1: read A-miL(q0/q2) + B-q(wn)  (gated: prev p4 vmcnt(2) drained Bq*,Aq0,Aq2)
//       issue Bq0,Bq1(t+1)           -> 4 outstanding
//   p2: read B hi-frags; issue Bq2,Bq3(t+1) -> 6; after MFMA: vmcnt(4)
//       (drains Aq1,Aq3(t), leaves 4)  + barrier
//   p3: read A-miH(q1/q3) (just drained); issue Aq0,Aq2(t+1) -> 6
//   p4: no reads; issue Aq1,Aq3(t+1) -> 8; after MFMA: vmcnt(2)
//       (drains Bq*,Aq0,Aq2(t+1), leaves Aq1,Aq3(t+1)=2) + barrier
// Prologue stages tile0 fully then vmcnt(2); tail tile stages nothing,
// uses vmcnt(0) drains.
//
// Buffer plan:
//   d_out: [0,16)  xb = bf16(x)          (dead after QKV GEMM)
//          [16,32) qb = bf16((xWq+bq)/8) (dead after attention)
//          [32,96) cache f32             (final output, written by QKV GEMM)
//          O GEMM overwrites [0,32) with out f32 at the end.
//   d_ws:  [0,24)  WT3 = bf16 [Wq;Wk;Wv]^T (dead after QKV GEMM)
//          then [0,8) WTo = bf16 Wo^T, [8,24) ctxb = bf16 attention out.

typedef __hip_bfloat16 bf16;
typedef unsigned short us;
typedef short s16x8 __attribute__((ext_vector_type(8)));
typedef float f32x4 __attribute__((ext_vector_type(4)));

#define T_SEQ   1024
#define D_MODEL 2048

__device__ inline us f2b(float f) {
    bf16 h = __float2bfloat16(f);
    return *(us*)&h;
}

typedef __attribute__((address_space(1))) const void gas_void;
typedef __attribute__((address_space(3))) void las_void;

__device__ inline void gl2lds16(const void* g, void* l) {
    // per-lane global src; LDS dest = wave-uniform base + lane*16
    __builtin_amdgcn_global_load_lds((gas_void*)g, (las_void*)l, 16, 0, 0);
}

#define VMC(n) asm volatile("s_waitcnt vmcnt(" #n ")" ::: "memory")

// ---------------------------------------------------------------------------
// x[4096][2048] f32 -> bf16 (linear)
// ---------------------------------------------------------------------------
__global__ __launch_bounds__(256)
void cvtx_kernel(const float* __restrict__ x, us* __restrict__ xb)
{
    const size_t i = ((size_t)blockIdx.x * 256 + threadIdx.x) * 8;
    float4 a = *(const float4*)(x + i);
    float4 b = *(const float4*)(x + i + 4);
    union { uint4 u; us s[8]; } p;
    p.s[0] = f2b(a.x); p.s[1] = f2b(a.y); p.s[2] = f2b(a.z); p.s[3] = f2b(a.w);
    p.s[4] = f2b(b.x); p.s[5] = f2b(b.y); p.s[6] = f2b(b.z); p.s[7] = f2b(b.w);
    *(uint4*)(xb + i) = p.u;
}

// ---------------------------------------------------------------------------
// W[2048][2048] f32 (k-major) -> Wt + z*2048*2048: bf16 [N][K] (k contiguous).
// ---------------------------------------------------------------------------
__global__ __launch_bounds__(256)
void wtrans_kernel(const float* __restrict__ W0, const float* __restrict__ W1,
                   const float* __restrict__ W2, us* __restrict__ Wt)
{
    __shared__ float tile[64][65];
    const int z = blockIdx.z;
    const float* W = (z == 0) ? W0 : (z == 1) ? W1 : W2;
    us* dst = Wt + (size_t)z * D_MODEL * D_MODEL;

    const int tid = threadIdx.x;
    const int k0 = blockIdx.y * 64, n0 = blockIdx.x * 64;

    const int rr = tid >> 4, cc = (tid & 15) * 4;
    #pragma unroll
    for (int i = 0; i < 4; ++i) {
        float4 v = *(const float4*)(W + (size_t)(k0 + rr + i * 16) * D_MODEL + n0 + cc);
        tile[rr + i * 16][cc]     = v.x;
        tile[rr + i * 16][cc + 1] = v.y;
        tile[rr + i * 16][cc + 2] = v.z;
        tile[rr + i * 16][cc + 3] = v.w;
    }
    __syncthreads();

    const int nr = tid >> 3, kc = (tid & 7) * 8;
    #pragma unroll
    for (int i = 0; i < 2; ++i) {
        const int n = nr + i * 32;
        union { uint4 u; us s[8]; } p;
        #pragma unroll
        for (int j = 0; j < 8; ++j) p.s[j] = f2b(tile[kc + j][n]);
        *(uint4*)(dst + (size_t)(n0 + n) * D_MODEL + k0 + kc) = p.u;
    }
}

// ---------------------------------------------------------------------------
// 256x256 8-phase GEMM: C[4096, N] = A(bf16) @ Bt^T + bias.
// MODE 0: f32 out (out0), bias b0.                       (O GEMM)
// MODE 3: col routing by n0>>11: 0 -> bf16 qb scaled 1/8 (bias b0),
//         1/2 -> f32 cache slot 0/1 (bias b1/b2).        (QKV GEMM)
// ---------------------------------------------------------------------------
template<int MODE>
__global__ __launch_bounds__(512, 2)
void gemm256_kernel(const us* __restrict__ A, const us* __restrict__ Bt,
                    const float* __restrict__ b0, const float* __restrict__ b1,
                    const float* __restrict__ b2,
                    float* __restrict__ out0, float* __restrict__ out1,
                    const int* __restrict__ idxp)
{
    // 2 bufs x 4 quarters x (64 rows x 64 k) for A and B = 128 KiB
    __shared__ __align__(16) us As[2 * 16384];
    __shared__ __align__(16) us Bs[2 * 16384];

    const int tid  = threadIdx.x;
    const int wv   = tid >> 6;       // 0..7
    const int lane = tid & 63;
    const int quad = lane >> 4;
    const int l15  = lane & 15;
    const int wm   = wv >> 2;        // 0..1  (M half: rows wm*128..+127)
    const int wn   = wv & 3;         // 0..3  (N quarter: cols wn*64..+63)
    const int m0   = blockIdx.y * 256;
    const int n0   = blockIdx.x * 256;

    // staging: thread covers (row srow of a 64-row quarter, swizzled 8-elem chunk)
    const int srow = wv * 8 + (lane >> 3);
    const int scol = ((lane & 7) ^ ((lane >> 3) & 7)) * 8;   // inverse-swizzled src
    const us* aG = A  + (size_t)(m0 + srow) * D_MODEL + scol;
    const us* bG = Bt + (size_t)(n0 + srow) * D_MODEL + scol;
    us* aD = As + wv * 512;          // + buf*16384 + quarter*4096 (wave-uniform)
    us* bD = Bs + wv * 512;

    // frag-read swizzle: chunk ^= (row&7); row&7 == l15&7 for 16-aligned rows
    const int xq = l15 & 7;

    f32x4 acc[8][4];
    #pragma unroll
    for (int mi = 0; mi < 8; ++mi)
        #pragma unroll
        for (int ni = 0; ni < 4; ++ni) acc[mi][ni] = f32x4{0.f, 0.f, 0.f, 0.f};

    // A frag (mi 0..7, kk 0..1): quarter wm*2+(mi>>2), row (mi&3)*16+l15
    #define LDA(BUF, MI, KK) \
        (*(const s16x8*)(As + (BUF)*16384 + (wm*2 + ((MI)>>2))*4096 \
            + (((MI)&3)*16 + l15)*64 + ((((KK)*4 + quad) ^ xq) * 8)))
    // B frag (ni 0..3, kk 0..1): quarter wn, row ni*16+l15
    #define LDB(BUF, NI, KK) \
        (*(const s16x8*)(Bs + (BUF)*16384 + wn*4096 \
            + ((NI)*16 + l15)*64 + ((((KK)*4 + quad) ^ xq) * 8)))

    #define STAGE_B01(NB, KOF) { gl2lds16(bG + (KOF),             bD + (NB)*16384);          \
                                 gl2lds16(bG + (KOF) +  64*D_MODEL, bD + (NB)*16384 + 4096); }
    #define STAGE_B23(NB, KOF) { gl2lds16(bG + (KOF) + 128*D_MODEL, bD + (NB)*16384 + 8192);  \
                                 gl2lds16(bG + (KOF) + 192*D_MODEL, bD + (NB)*16384 + 12288); }
    #define STAGE_A02(NB, KOF) { gl2lds16(aG + (KOF),             aD + (NB)*16384);          \
                                 gl2lds16(aG + (KOF) + 128*D_MODEL, aD + (NB)*16384 + 8192); }
    #define STAGE_A13(NB, KOF) { gl2lds16(aG + (KOF) +  64*D_MODEL, aD + (NB)*16384 + 4096);  \
                                 gl2lds16(aG + (KOF) + 192*D_MODEL, aD + (NB)*16384 + 12288); }

    // ---- prologue: stage tile 0 into buf 0 (issue order = steady-state) ----
    STAGE_B01(0, 0); STAGE_B23(0, 0); STAGE_A02(0, 0); STAGE_A13(0, 0);
    VMC(2);                      // drain Bq*, Aq0, Aq2; leave Aq1,Aq3 in flight
    __builtin_amdgcn_s_barrier();

    #define KTILE(BUF, STG, KOFN, VM2STMT, VM4STMT) do {                          \
        s16x8 aL[4][2], aH[4][2], bF0[2][2], bF1[2][2];                           \
        /* phase 1: miL x niL */                                                  \
        _Pragma("unroll") for (int mi = 0; mi < 4; ++mi)                          \
            _Pragma("unroll") for (int kk = 0; kk < 2; ++kk)                      \
                aL[mi][kk] = LDA(BUF, mi, kk);                                    \
        _Pragma("unroll") for (int ni = 0; ni < 2; ++ni)                          \
            _Pragma("unroll") for (int kk = 0; kk < 2; ++kk)                      \
                bF0[ni][kk] = LDB(BUF, ni, kk);                                   \
        if (STG) STAGE_B01((BUF)^1, KOFN);                                        \
        __builtin_amdgcn_s_barrier();                                             \
        __builtin_amdgcn_s_setprio(1);                                            \
        _Pragma("unroll") for (int kk = 0; kk < 2; ++kk)                          \
            _Pragma("unroll") for (int mi = 0; mi < 4; ++mi)                      \
                _Pragma("unroll") for (int ni = 0; ni < 2; ++ni)                  \
                    acc[mi][ni] = __builtin_amdgcn_mfma_f32_16x16x32_bf16(        \
                        aL[mi][kk], bF0[ni][kk], acc[mi][ni], 0, 0, 0);           \
        __builtin_amdgcn_s_setprio(0);                                            \
        __builtin_amdgcn_s_barrier();                                             \
        /* phase 2: miL x niH */                                                  \
        _Pragma("unroll") for (int ni = 0; ni < 2; ++ni)                          \
            _Pragma("unroll") for (int kk = 0; kk < 2; ++kk)                      \
                bF1[ni][kk] = LDB(BUF, 2 + ni, kk);                               \
        if (STG) STAGE_B23((BUF)^1, KOFN);                                        \
        __builtin_amdgcn_s_barrier();                                             \
        __builtin_amdgcn_s_setprio(1);                                            \
        _Pragma("unroll") for (int kk = 0; kk < 2; ++kk)                          \
            _Pragma("unroll") for (int mi = 0; mi < 4; ++mi)                      \
                _Pragma("unroll") for (int ni = 0; ni < 2; ++ni)                  \
                    acc[mi][2 + ni] = __builtin_amdgcn_mfma_f32_16x16x32_bf16(    \
                        aL[mi][kk], bF1[ni][kk], acc[mi][2 + ni], 0, 0, 0);       \
        __builtin_amdgcn_s_setprio(0);                                            \
        VM2STMT;                                                                  \
        __builtin_amdgcn_s_barrier();                                             \
        /* phase 3: miH x niH */                                                  \
        _Pragma("unroll") for (int mi = 0; mi < 4; ++mi)                          \
            _Pragma("unroll") for (int kk = 0; kk < 2; ++kk)                      \
                aH[mi][kk] = LDA(BUF, 4 + mi, kk);                                \
        if (STG) STAGE_A02((BUF)^1, KOFN);                                        \
        __builtin_amdgcn_s_barrier();                                             \
        __builtin_amdgcn_s_setprio(1);                                            \
        _Pragma("unroll") for (int kk = 0; kk < 2; ++kk)                          \
            _Pragma("unroll") for (int mi = 0; mi < 4; ++mi)                      \
                _Pragma("unroll") for (int ni = 0; ni < 2; ++ni)                  \
                    acc[4 + mi][2 + ni] = __builtin_amdgcn_mfma_f32_16x16x32_bf16(\
                        aH[mi][kk], bF1[ni][kk], acc[4 + mi][2 + ni], 0, 0, 0);   \
        __builtin_amdgcn_s_setprio(0);                                            \
        __builtin_amdgcn_s_barrier();                                             \
        /* phase 4: miH x niL (no new frags) */                                   \
        if (STG) STAGE_A13((BUF)^1, KOFN);                                        \
        __builtin_amdgcn_s_barrier();                                             \
        __builtin_amdgcn_s_setprio(1);                                            \
        _Pragma("unroll") for (int kk = 0; kk < 2; ++kk)                          \
            _Pragma("unroll") for (int mi = 0; mi < 4; ++mi)                      \
                _Pragma("unroll") for (int ni = 0; ni < 2; ++ni)                  \
                    acc[4 + mi][ni] = __builtin_amdgcn_mfma_f32_16x16x32_bf16(    \
                        aH[mi][kk], bF0[ni][kk], acc[4 + mi][ni], 0, 0, 0);       \
        __builtin_amdgcn_s_setprio(0);                                            \
        VM4STMT;                                                                  \
        __builtin_amdgcn_s_barrier();                                             \
    } while (0)

    // main loop: tiles 0..30, staging tile t+1
    for (int t = 0; t < 31; ++t) {
        const int buf = t & 1;
        const int kofn = (t + 1) * 64;
        if (buf == 0) KTILE(0, true, kofn, VMC(4), VMC(2));
        else          KTILE(1, true, kofn, VMC(4), VMC(2));
    }
    // tail: tile 31, no staging; drain fully
    KTILE(1, false, 0, VMC(0), VMC(0));

    // ---- epilogue ----
    const int seg = (MODE == 3) ? (n0 >> 11) : 0;
    const float* bias = (MODE == 3) ? (seg == 0 ? b0 : (seg == 1 ? b1 : b2)) : b0;
    const int idx = (MODE == 3 && seg > 0) ? idxp[0] : 0;

    #pragma unroll
    for (int ni = 0; ni < 4; ++ni) {
        const int col = n0 + wn * 64 + ni * 16 + l15;
        const int cl  = col & (D_MODEL - 1);
        const float bv = bias[cl];
        #pragma unroll
        for (int mi = 0; mi < 8; ++mi) {
            #pragma unroll
            for (int r = 0; r < 4; ++r) {
                const int m = m0 + wm * 128 + (mi >> 2) * 64 + (mi & 3) * 16 + quad * 4 + r;
                const float v = acc[mi][ni][r] + bv;
                if (MODE == 0) {
                    out0[(size_t)m * D_MODEL + cl] = v;
                } else {
                    if (seg == 0) {
                        ((us*)out0)[(size_t)m * D_MODEL + cl] = f2b(v * 0.125f);
                    } else {
                        const int b  = m >> 10;
                        const int tt = ((m & 1023) + idx) & 1023;
                        out1[((size_t)(b * 2 + (seg - 1)) * T_SEQ + tt) * D_MODEL + cl] = v;
                    }
                }
            }
        }
    }
    #undef LDA
    #undef LDB
    #undef STAGE_B01
    #undef STAGE_B23
    #undef STAGE_A02
    #undef STAGE_A13
    #undef KTILE
}

// ---------------------------------------------------------------------------
// MFMA flash attention, QBLK=128 (unchanged from R4).
// ---------------------------------------------------------------------------
#define LDW  72
#define LDWV 70

__global__ __launch_bounds__(512, 6)
void attn_mfma_kernel(const us* __restrict__ q, const float* __restrict__ cache,
                      us* __restrict__ ctx)
{
    __shared__ __align__(16) us Qs[128 * LDW];   // Q tile; reused as Ps after hoist
    __shared__ __align__(16) us Ks[64 * LDW];    // Ks[key][d]
    __shared__ __align__(16) us Vt[64 * LDWV];   // Vt[d][key]

    const int tid  = threadIdx.x;
    const int wave = tid >> 6;          // 0..7
    const int lane = tid & 63;
    const int quad = lane >> 4;
    const int l15  = lane & 15;

    const int bh = blockIdx.x;          // b*32 + h
    const int b  = bh >> 5;
    const int h  = bh & 31;
    const int qt = 7 - blockIdx.y;      // query tile 0..7 (128 rows each)

    const float* kbase = cache + ((size_t)(b * 2 + 0) * T_SEQ) * D_MODEL + h * 64;
    const float* vbase = cache + ((size_t)(b * 2 + 1) * T_SEQ) * D_MODEL + h * 64;

    {
        const int qrow = tid >> 2;
        const int qp   = tid & 3;
        const uint4* qg = (const uint4*)(q + (size_t)(b * T_SEQ + qt * 128 + qrow) * D_MODEL
                                           + h * 64 + qp * 16);
        uint4 q0 = qg[0], q1 = qg[1];
        *(uint4*)(Qs + qrow * LDW + qp * 16)     = q0;
        *(uint4*)(Qs + qrow * LDW + qp * 16 + 8) = q1;
    }
    __syncthreads();

    const s16x8 qf0 = *(const s16x8*)(Qs + (wave * 16 + l15) * LDW + quad * 8);
    const s16x8 qf1 = *(const s16x8*)(Qs + (wave * 16 + l15) * LDW + 32 + quad * 8);

    f32x4 oacc[4];
    #pragma unroll
    for (int t = 0; t < 4; ++t) oacc[t] = f32x4{0.f, 0.f, 0.f, 0.f};
    float m_run[4] = {-1e30f, -1e30f, -1e30f, -1e30f};
    float l_run[4] = {0.f, 0.f, 0.f, 0.f};

    const int nkt = 2 * qt + 2;

    const int ksrow = tid >> 3;
    const int kp8   = tid & 7;
    const int vs    = tid >> 4;
    const int vp4   = tid & 15;

    for (int kt = 0; kt < nkt; ++kt) {
        __syncthreads();

        {
            const float4* kg = (const float4*)(kbase + (size_t)(kt * 64 + ksrow) * D_MODEL + kp8 * 8);
            float4 k0 = kg[0], k1 = kg[1];
            union { uint4 u; us s[8]; } p;
            p.s[0] = f2b(k0.x); p.s[1] = f2b(k0.y); p.s[2] = f2b(k0.z); p.s[3] = f2b(k0.w);
            p.s[4] = f2b(k1.x); p.s[5] = f2b(k1.y); p.s[6] = f2b(k1.z); p.s[7] = f2b(k1.w);
            *(uint4*)(Ks + ksrow * LDW + kp8 * 8) = p.u;
        }
        {
            const float4 a = *(const float4*)(vbase + (size_t)(kt * 64 + 2 * vs) * D_MODEL + vp4 * 4);
            const float4 c = *(const float4*)(vbase + (size_t)(kt * 64 + 2 * vs + 1) * D_MODEL + vp4 * 4);
            const float av[4] = {a.x, a.y, a.z, a.w};
            const float cv[4] = {c.x, c.y, c.z, c.w};
            #pragma unroll
            for (int j = 0; j < 4; ++j) {
                ushort2 w; w.x = f2b(av[j]); w.y = f2b(cv[j]);
                *(ushort2*)(Vt + (vp4 * 4 + j) * LDWV + 2 * vs) = w;
            }
        }
        __syncthreads();

        const int kbr = kt * 64 - qt * 128;
        if (kbr < wave * 16 + 16) {
            f32x4 sacc[4];
            #pragma unroll
            for (int t = 0; t < 4; ++t) sacc[t] = f32x4{0.f, 0.f, 0.f, 0.f};
            #pragma unroll
            for (int t = 0; t < 4; ++t) {
                s16x8 kf0 = *(const s16x8*)(Ks + (t * 16 + l15) * LDW + quad * 8);
                s16x8 kf1 = *(const s16x8*)(Ks + (t * 16 + l15) * LDW + 32 + quad * 8);
                sacc[t] = __builtin_amdgcn_mfma_f32_16x16x32_bf16(qf0, kf0, sacc[t], 0, 0, 0);
                sacc[t] = __builtin_amdgcn_mfma_f32_16x16x32_bf16(qf1, kf1, sacc[t], 0, 0, 0);
            }

            if (kbr + 63 > wave * 16) {
                #pragma unroll
                for (int t = 0; t < 4; ++t) {
                    const int keyl = kbr + t * 16 + l15;
                    #pragma unroll
                    for (int r = 0; r < 4; ++r) {
                        if (keyl > wave * 16 + quad * 4 + r) sacc[t][r] = -1e30f;
                    }
                }
            }

            float rmax[4];
            #pragma unroll
            for (int r = 0; r < 4; ++r)
                rmax[r] = fmaxf(fmaxf(sacc[0][r], sacc[1][r]), fmaxf(sacc[2][r], sacc[3][r]));
            #pragma unroll
            for (int off = 1; off < 16; off <<= 1) {
                #pragma unroll
                for (int r = 0; r < 4; ++r) rmax[r] = fmaxf(rmax[r], __shfl_xor(rmax[r], off, 16));
            }
            float alpha[4];
            #pragma unroll
            for (int r = 0; r < 4; ++r) {
                const float mnew = fmaxf(m_run[r], rmax[r]);
                alpha[r] = __expf(m_run[r] - mnew);
                m_run[r] = mnew;
            }
            float rsum[4] = {0.f, 0.f, 0.f, 0.f};
            #pragma unroll
            for (int t = 0; t < 4; ++t) {
                #pragma unroll
                for (int r = 0; r < 4; ++r) {
                    const float p = __expf(sacc[t][r] - m_run[r]);
                    sacc[t][r] = p;
                    rsum[r] += p;
                }
            }
            #pragma unroll
            for (int off = 1; off < 16; off <<= 1) {
                #pragma unroll
                for (int r = 0; r < 4; ++r) rsum[r] += __shfl_xor(rsum[r], off, 16);
            }
            #pragma unroll
            for (int r = 0; r < 4; ++r) l_run[r] = l_run[r] * alpha[r] + rsum[r];
            #pragma unroll
            for (int t = 0; t < 4; ++t) {
                #pragma unroll
                for (int r = 0; r < 4; ++r) oacc[t][r] *= alpha[r];
            }

            #pragma unroll
            for (int t = 0; t < 4; ++t) {
                #pragma unroll
                for (int r = 0; r < 4; ++r)
                    Qs[(wave * 16 + quad * 4 + r) * LDW + t * 16 + l15] = f2b(sacc[t][r]);
            }

            s16x8 pf0 = *(const s16x8*)(Qs + (wave * 16 + l15) * LDW + quad * 8);
            s16x8 pf1 = *(const s16x8*)(Qs + (wave * 16 + l15) * LDW + 32 + quad * 8);
            #pragma unroll
            for (int t = 0; t < 4; ++t) {
                s16x8 vf0 = *(const s16x8*)(Vt + (t * 16 + l15) * LDWV + quad * 8);
                s16x8 vf1 = *(const s16x8*)(Vt + (t * 16 + l15) * LDWV + 32 + quad * 8);
                oacc[t] = __builtin_amdgcn_mfma_f32_16x16x32_bf16(pf0, vf0, oacc[t], 0, 0, 0);
                oacc[t] = __builtin_amdgcn_mfma_f32_16x16x32_bf16(pf1, vf1, oacc[t], 0, 0, 0);
            }
        }
    }

    float invl[4];
    #pragma unroll
    for (int r = 0; r < 4; ++r) invl[r] = 1.0f / l_run[r];
    #pragma unroll
    for (int r = 0; r < 4; ++r) {
        const int qrow = qt * 128 + wave * 16 + quad * 4 + r;
        us* orow = ctx + (size_t)(b * T_SEQ + qrow) * D_MODEL + h * 64;
        #pragma unroll
        for (int t = 0; t < 4; ++t) orow[t * 16 + l15] = f2b(oacc[t][r] * invl[r]);
    }
}

// ---------------------------------------------------------------------------
extern "C" void kernel_launch(void* const* d_in, const int* in_sizes, int n_in,
                              void* d_out, int out_size, void* d_ws, size_t ws_size,
                              hipStream_t stream)
{
    const float* x    = (const float*)d_in[0];
    const int*   idxp = (const int*)d_in[3];
    const float* Wq   = (const float*)d_in[4];
    const float* bq   = (const float*)d_in[5];
    const float* Wk   = (const float*)d_in[6];
    const float* bk   = (const float*)d_in[7];
    const float* Wv   = (const float*)d_in[8];
    const float* bv   = (const float*)d_in[9];
    const float* Wo   = (const float*)d_in[10];
    const float* bo   = (const float*)d_in[11];

    float* out      = (float*)d_out;
    us*    xb       = (us*)d_out;                                   // [0,16MB)
    us*    qb       = (us*)d_out + (size_t)8 * 1024 * 1024;         // [16,32MB)
    float* cacheOut = out + (size_t)4 * T_SEQ * D_MODEL;            // [32,96MB)

    us* WT3  = (us*)d_ws;                                           // [0,24MB)
    us* WTo  = (us*)d_ws;                                           // [0,8MB)  (after QKV)
    us* ctxb = (us*)d_ws + (size_t)4 * 1024 * 1024;                 // [8,24MB)

    const dim3 tb(256);

    cvtx_kernel<<<dim3(4096), tb, 0, stream>>>(x, xb);
    wtrans_kernel<<<dim3(32, 32, 3), tb, 0, stream>>>(Wq, Wk, Wv, WT3);

    // fused QKV: N = 6144, 256x256 tiles -> 24 x 16 = 384 blocks
    gemm256_kernel<3><<<dim3(24, 16), dim3(512), 0, stream>>>(
        xb, WT3, bq, bk, bv, (float*)qb, cacheOut, idxp);

    wtrans_kernel<<<dim3(32, 32, 1), tb, 0, stream>>>(Wo, Wo, Wo, WTo);

    attn_mfma_kernel<<<dim3(128, 8), dim3(512), 0, stream>>>(qb, cacheOut, ctxb);

    // O GEMM: N = 2048 -> 8 x 16 = 128 blocks
    gemm256_kernel<0><<<dim3(8, 16), dim3(512), 0, stream>>>(
        ctxb, WTo, bo, nullptr, nullptr, out, nullptr, nullptr);
}

// Round 4
// 438.953 us; speedup vs baseline: 2.9628x; 2.9628x over previous
//
#include <hip/hip_runtime.h>
#include <hip/hip_bf16.h>
#include <stdint.h>

// CachedOPTAttention: B=4, T=1024, D=2048, H=32, HD=64, causal, idx=0.
// FP32 buffers; bf16-class error budget -> bf16 MFMA math inside.
//
// R6: revert the spilling 256^2 8-phase (R5: scratch traffic 1.37GB/dispatch).
// Keep the m97-class 128^2 / 4-wave / single-buffer / 2-barrier GEMM (R4:
// 632 TF fused QKV) and add low-register-pressure upgrades:
//   * BK=64: halves K-iterations (64->32) -> halves barrier-drain count.
//   * R5's proven XOR LDS swizzle (pre-swizzled global source, swizzled
//     frag reads) -> measured ZERO bank conflicts in R5.
//   * bijective XCD blockIdx swizzle (grids 1536 / 512, both % 8 == 0).
//   * attention __launch_bounds__(512,6)->(512,4): R4's cap ~85 VGPR was
//     below the kernel's ~110 need (suspected spill).
//
// Buffer plan:
//   d_out: [0,16)  xb = bf16(x)          (dead after QKV GEMM)
//          [16,32) qb = bf16((xWq+bq)/8) (dead after attention)
//          [32,96) cache f32             (final output, written by QKV GEMM)
//          O GEMM overwrites [0,32) with out f32 at the end.
//   d_ws:  [0,24)  WT3 = bf16 [Wq;Wk;Wv]^T (dead after QKV GEMM)
//          then [0,8) WTo = bf16 Wo^T, [8,24) ctxb = bf16 attention out.

typedef __hip_bfloat16 bf16;
typedef unsigned short us;
typedef short s16x8 __attribute__((ext_vector_type(8)));
typedef float f32x4 __attribute__((ext_vector_type(4)));

#define T_SEQ   1024
#define D_MODEL 2048

__device__ inline us f2b(float f) {
    bf16 h = __float2bfloat16(f);
    return *(us*)&h;
}

typedef __attribute__((address_space(1))) const void gas_void;
typedef __attribute__((address_space(3))) void las_void;

__device__ inline void gl2lds16(const void* g, void* l) {
    // per-lane global src; LDS dest = wave-uniform base + lane*16
    __builtin_amdgcn_global_load_lds((gas_void*)g, (las_void*)l, 16, 0, 0);
}

// ---------------------------------------------------------------------------
// x[4096][2048] f32 -> bf16 (linear)
// ---------------------------------------------------------------------------
__global__ __launch_bounds__(256)
void cvtx_kernel(const float* __restrict__ x, us* __restrict__ xb)
{
    const size_t i = ((size_t)blockIdx.x * 256 + threadIdx.x) * 8;
    float4 a = *(const float4*)(x + i);
    float4 b = *(const float4*)(x + i + 4);
    union { uint4 u; us s[8]; } p;
    p.s[0] = f2b(a.x); p.s[1] = f2b(a.y); p.s[2] = f2b(a.z); p.s[3] = f2b(a.w);
    p.s[4] = f2b(b.x); p.s[5] = f2b(b.y); p.s[6] = f2b(b.z); p.s[7] = f2b(b.w);
    *(uint4*)(xb + i) = p.u;
}

// ---------------------------------------------------------------------------
// W[2048][2048] f32 (k-major) -> Wt + z*2048*2048: bf16 [N][K] (k contiguous).
// ---------------------------------------------------------------------------
__global__ __launch_bounds__(256)
void wtrans_kernel(const float* __restrict__ W0, const float* __restrict__ W1,
                   const float* __restrict__ W2, us* __restrict__ Wt)
{
    __shared__ float tile[64][65];
    const int z = blockIdx.z;
    const float* W = (z == 0) ? W0 : (z == 1) ? W1 : W2;
    us* dst = Wt + (size_t)z * D_MODEL * D_MODEL;

    const int tid = threadIdx.x;
    const int k0 = blockIdx.y * 64, n0 = blockIdx.x * 64;

    const int rr = tid >> 4, cc = (tid & 15) * 4;
    #pragma unroll
    for (int i = 0; i < 4; ++i) {
        float4 v = *(const float4*)(W + (size_t)(k0 + rr + i * 16) * D_MODEL + n0 + cc);
        tile[rr + i * 16][cc]     = v.x;
        tile[rr + i * 16][cc + 1] = v.y;
        tile[rr + i * 16][cc + 2] = v.z;
        tile[rr + i * 16][cc + 3] = v.w;
    }
    __syncthreads();

    const int nr = tid >> 3, kc = (tid & 7) * 8;
    #pragma unroll
    for (int i = 0; i < 2; ++i) {
        const int n = nr + i * 32;
        union { uint4 u; us s[8]; } p;
        #pragma unroll
        for (int j = 0; j < 8; ++j) p.s[j] = f2b(tile[kc + j][n]);
        *(uint4*)(dst + (size_t)(n0 + n) * D_MODEL + k0 + kc) = p.u;
    }
}

// ---------------------------------------------------------------------------
// GEMM (m97 structure, BK=64): C[4096, N] = A(bf16) @ Bt^T + bias.
// Bt bf16 [N][K] k-contiguous. Tile 128x128, 4 waves (2x2), wave tile 64x64.
// LDS: As/Bs [128 rows][64 k] linear, XOR-swizzled chunks:
//   LDS[row][chunk] = G[row][chunk ^ (row&7)]   (chunk = 8 bf16 = 16B)
// staged via pre-swizzled global source (gl2lds dest stays linear), read back
// with the same XOR -> zero bank conflicts (proven in R5).
// MODE 0: f32 out (out0), bias b0.                       (O GEMM)
// MODE 3: col routing by n0>>11: 0 -> bf16 qb scaled 1/8 (bias b0),
//         1/2 -> f32 cache slot 0/1 (bias b1/b2).        (QKV GEMM)
// ---------------------------------------------------------------------------
template<int MODE>
__global__ __launch_bounds__(256, 3)
void gemm128_kernel(const us* __restrict__ A, const us* __restrict__ Bt,
                    const float* __restrict__ b0, const float* __restrict__ b1,
                    const float* __restrict__ b2,
                    float* __restrict__ out0, float* __restrict__ out1,
                    const int* __restrict__ idxp)
{
    __shared__ __align__(16) us As[128 * 64];   // 16 KB
    __shared__ __align__(16) us Bs[128 * 64];   // 16 KB

    const int tid  = threadIdx.x;
    const int wv   = tid >> 6;       // 0..3
    const int lane = tid & 63;
    const int quad = lane >> 4;
    const int l15  = lane & 15;
    const int wm   = wv >> 1;        // 0..1
    const int wn   = wv & 1;         // 0..1

    // bijective XCD swizzle: nwg % 8 == 0 for both grids (1536, 512)
    const int gx  = gridDim.x;
    const int nwg = gx * gridDim.y;
    int bid = blockIdx.y * gx + blockIdx.x;
    bid = (bid & 7) * (nwg >> 3) + (bid >> 3);
    const int m0 = (bid / gx) * 128;
    const int n0 = (bid % gx) * 128;

    // staging: wave wv covers 32 rows (wv*32..+31); per gl2lds: 8 rows.
    // lane l -> row (l>>3), source chunk (l&7)^(l>>3)  (inverse swizzle)
    const int srow = lane >> 3;                       // 0..7
    const int scol = ((lane & 7) ^ srow) * 8;         // pre-swizzled k offset
    const us* aG = A  + (size_t)(m0 + wv * 32 + srow) * D_MODEL + scol;
    const us* bG = Bt + (size_t)(n0 + wv * 32 + srow) * D_MODEL + scol;
    us* aL = As + wv * 32 * 64;
    us* bL = Bs + wv * 32 * 64;

    f32x4 acc[4][4];
    #pragma unroll
    for (int mi = 0; mi < 4; ++mi)
        #pragma unroll
        for (int ni = 0; ni < 4; ++ni) acc[mi][ni] = f32x4{0.f, 0.f, 0.f, 0.f};

    // frag read: row = (wm|wn)*64 + t*16 + l15; k chunk (kk*4+quad) ^ (row&7)
    const int xr = l15 & 7;
    #define LDA(MI, KK) (*(const s16x8*)(As + (wm * 64 + (MI) * 16 + l15) * 64 \
                          + ((((KK) * 4 + quad) ^ xr) * 8)))
    #define LDB(NI, KK) (*(const s16x8*)(Bs + (wn * 64 + (NI) * 16 + l15) * 64 \
                          + ((((KK) * 4 + quad) ^ xr) * 8)))

    for (int k0 = 0; k0 < D_MODEL; k0 += 64) {
        #pragma unroll
        for (int g = 0; g < 4; ++g) {
            gl2lds16(aG + k0 + g * 8 * D_MODEL, aL + g * 512);
            gl2lds16(bG + k0 + g * 8 * D_MODEL, bL + g * 512);
        }
        __syncthreads();   // compiler emits vmcnt(0) drain before barrier

        #pragma unroll
        for (int kk = 0; kk < 2; ++kk) {
            s16x8 af[4], bfr[4];
            #pragma unroll
            for (int mi = 0; mi < 4; ++mi) af[mi] = LDA(mi, kk);
            #pragma unroll
            for (int ni = 0; ni < 4; ++ni) bfr[ni] = LDB(ni, kk);
            #pragma unroll
            for (int mi = 0; mi < 4; ++mi)
                #pragma unroll
                for (int ni = 0; ni < 4; ++ni)
                    acc[mi][ni] = __builtin_amdgcn_mfma_f32_16x16x32_bf16(
                        af[mi], bfr[ni], acc[mi][ni], 0, 0, 0);
        }
        __syncthreads();   // frag reads done before restage
    }
    #undef LDA
    #undef LDB

    const int seg = (MODE == 3) ? (n0 >> 11) : 0;
    const float* bias = (MODE == 3) ? (seg == 0 ? b0 : (seg == 1 ? b1 : b2)) : b0;
    const int idx = (MODE == 3 && seg > 0) ? idxp[0] : 0;

    #pragma unroll
    for (int ni = 0; ni < 4; ++ni) {
        const int col = n0 + wn * 64 + ni * 16 + l15;
        const int cl  = col & (D_MODEL - 1);
        const float bv = bias[cl];
        #pragma unroll
        for (int mi = 0; mi < 4; ++mi) {
            #pragma unroll
            for (int r = 0; r < 4; ++r) {
                const int m = m0 + wm * 64 + mi * 16 + quad * 4 + r;
                const float v = acc[mi][ni][r] + bv;
                if (MODE == 0) {
                    out0[(size_t)m * D_MODEL + cl] = v;
                } else {
                    if (seg == 0) {
                        ((us*)out0)[(size_t)m * D_MODEL + cl] = f2b(v * 0.125f);
                    } else {
                        const int b  = m >> 10;
                        const int tt = ((m & 1023) + idx) & 1023;
                        out1[((size_t)(b * 2 + (seg - 1)) * T_SEQ + tt) * D_MODEL + cl] = v;
                    }
                }
            }
        }
    }
}

// ---------------------------------------------------------------------------
// MFMA flash attention, QBLK=128: 512 thr = 8 waves, each wave owns 16 query
// rows. Per 64-key tile: stage K (row-major) + V (transposed, paired ushort2
// writes) from f32 cache; S=Q@K^T; in-register online softmax; P via LDS
// (reusing dead Qs); O += P@V^T. Fully-masked diagonal sub-tiles skipped.
// launch_bounds (512,4): VGPR cap 128 (R4's (512,6)=~85 was under-budget).
// ---------------------------------------------------------------------------
#define LDW  72
#define LDWV 70

__global__ __launch_bounds__(512, 4)
void attn_mfma_kernel(const us* __restrict__ q, const float* __restrict__ cache,
                      us* __restrict__ ctx)
{
    __shared__ __align__(16) us Qs[128 * LDW];   // Q tile; reused as Ps after hoist
    __shared__ __align__(16) us Ks[64 * LDW];    // Ks[key][d]
    __shared__ __align__(16) us Vt[64 * LDWV];   // Vt[d][key]

    const int tid  = threadIdx.x;
    const int wave = tid >> 6;          // 0..7
    const int lane = tid & 63;
    const int quad = lane >> 4;
    const int l15  = lane & 15;

    const int bh = blockIdx.x;          // b*32 + h
    const int b  = bh >> 5;
    const int h  = bh & 31;
    const int qt = 7 - blockIdx.y;      // query tile 0..7 (128 rows each)

    const float* kbase = cache + ((size_t)(b * 2 + 0) * T_SEQ) * D_MODEL + h * 64;
    const float* vbase = cache + ((size_t)(b * 2 + 1) * T_SEQ) * D_MODEL + h * 64;

    {
        const int qrow = tid >> 2;
        const int qp   = tid & 3;
        const uint4* qg = (const uint4*)(q + (size_t)(b * T_SEQ + qt * 128 + qrow) * D_MODEL
                                           + h * 64 + qp * 16);
        uint4 q0 = qg[0], q1 = qg[1];
        *(uint4*)(Qs + qrow * LDW + qp * 16)     = q0;
        *(uint4*)(Qs + qrow * LDW + qp * 16 + 8) = q1;
    }
    __syncthreads();

    const s16x8 qf0 = *(const s16x8*)(Qs + (wave * 16 + l15) * LDW + quad * 8);
    const s16x8 qf1 = *(const s16x8*)(Qs + (wave * 16 + l15) * LDW + 32 + quad * 8);

    f32x4 oacc[4];
    #pragma unroll
    for (int t = 0; t < 4; ++t) oacc[t] = f32x4{0.f, 0.f, 0.f, 0.f};
    float m_run[4] = {-1e30f, -1e30f, -1e30f, -1e30f};
    float l_run[4] = {0.f, 0.f, 0.f, 0.f};

    const int nkt = 2 * qt + 2;

    const int ksrow = tid >> 3;
    const int kp8   = tid & 7;
    const int vs    = tid >> 4;
    const int vp4   = tid & 15;

    for (int kt = 0; kt < nkt; ++kt) {
        __syncthreads();

        {
            const float4* kg = (const float4*)(kbase + (size_t)(kt * 64 + ksrow) * D_MODEL + kp8 * 8);
            float4 k0 = kg[0], k1 = kg[1];
            union { uint4 u; us s[8]; } p;
            p.s[0] = f2b(k0.x); p.s[1] = f2b(k0.y); p.s[2] = f2b(k0.z); p.s[3] = f2b(k0.w);
            p.s[4] = f2b(k1.x); p.s[5] = f2b(k1.y); p.s[6] = f2b(k1.z); p.s[7] = f2b(k1.w);
            *(uint4*)(Ks + ksrow * LDW + kp8 * 8) = p.u;
        }
        {
            const float4 a = *(const float4*)(vbase + (size_t)(kt * 64 + 2 * vs) * D_MODEL + vp4 * 4);
            const float4 c = *(const float4*)(vbase + (size_t)(kt * 64 + 2 * vs + 1) * D_MODEL + vp4 * 4);
            const float av[4] = {a.x, a.y, a.z, a.w};
            const float cv[4] = {c.x, c.y, c.z, c.w};
            #pragma unroll
            for (int j = 0; j < 4; ++j) {
                ushort2 w; w.x = f2b(av[j]); w.y = f2b(cv[j]);
                *(ushort2*)(Vt + (vp4 * 4 + j) * LDWV + 2 * vs) = w;
            }
        }
        __syncthreads();

        const int kbr = kt * 64 - qt * 128;
        if (kbr < wave * 16 + 16) {
            f32x4 sacc[4];
            #pragma unroll
            for (int t = 0; t < 4; ++t) sacc[t] = f32x4{0.f, 0.f, 0.f, 0.f};
            #pragma unroll
            for (int t = 0; t < 4; ++t) {
                s16x8 kf0 = *(const s16x8*)(Ks + (t * 16 + l15) * LDW + quad * 8);
                s16x8 kf1 = *(const s16x8*)(Ks + (t * 16 + l15) * LDW + 32 + quad * 8);
                sacc[t] = __builtin_amdgcn_mfma_f32_16x16x32_bf16(qf0, kf0, sacc[t], 0, 0, 0);
                sacc[t] = __builtin_amdgcn_mfma_f32_16x16x32_bf16(qf1, kf1, sacc[t], 0, 0, 0);
            }

            if (kbr + 63 > wave * 16) {
                #pragma unroll
                for (int t = 0; t < 4; ++t) {
                    const int keyl = kbr + t * 16 + l15;
                    #pragma unroll
                    for (int r = 0; r < 4; ++r) {
                        if (keyl > wave * 16 + quad * 4 + r) sacc[t][r] = -1e30f;
                    }
                }
            }

            float rmax[4];
            #pragma unroll
            for (int r = 0; r < 4; ++r)
                rmax[r] = fmaxf(fmaxf(sacc[0][r], sacc[1][r]), fmaxf(sacc[2][r], sacc[3][r]));
            #pragma unroll
            for (int off = 1; off < 16; off <<= 1) {
                #pragma unroll
                for (int r = 0; r < 4; ++r) rmax[r] = fmaxf(rmax[r], __shfl_xor(rmax[r], off, 16));
            }
            float alpha[4];
            #pragma unroll
            for (int r = 0; r < 4; ++r) {
                const float mnew = fmaxf(m_run[r], rmax[r]);
                alpha[r] = __expf(m_run[r] - mnew);
                m_run[r] = mnew;
            }
            float rsum[4] = {0.f, 0.f, 0.f, 0.f};
            #pragma unroll
            for (int t = 0; t < 4; ++t) {
                #pragma unroll
                for (int r = 0; r < 4; ++r) {
                    const float p = __expf(sacc[t][r] - m_run[r]);
                    sacc[t][r] = p;
                    rsum[r] += p;
                }
            }
            #pragma unroll
            for (int off = 1; off < 16; off <<= 1) {
                #pragma unroll
                for (int r = 0; r < 4; ++r) rsum[r] += __shfl_xor(rsum[r], off, 16);
            }
            #pragma unroll
            for (int r = 0; r < 4; ++r) l_run[r] = l_run[r] * alpha[r] + rsum[r];
            #pragma unroll
            for (int t = 0; t < 4; ++t) {
                #pragma unroll
                for (int r = 0; r < 4; ++r) oacc[t][r] *= alpha[r];
            }

            #pragma unroll
            for (int t = 0; t < 4; ++t) {
                #pragma unroll
                for (int r = 0; r < 4; ++r)
                    Qs[(wave * 16 + quad * 4 + r) * LDW + t * 16 + l15] = f2b(sacc[t][r]);
            }

            s16x8 pf0 = *(const s16x8*)(Qs + (wave * 16 + l15) * LDW + quad * 8);
            s16x8 pf1 = *(const s16x8*)(Qs + (wave * 16 + l15) * LDW + 32 + quad * 8);
            #pragma unroll
            for (int t = 0; t < 4; ++t) {
                s16x8 vf0 = *(const s16x8*)(Vt + (t * 16 + l15) * LDWV + quad * 8);
                s16x8 vf1 = *(const s16x8*)(Vt + (t * 16 + l15) * LDWV + 32 + quad * 8);
                oacc[t] = __builtin_amdgcn_mfma_f32_16x16x32_bf16(pf0, vf0, oacc[t], 0, 0, 0);
                oacc[t] = __builtin_amdgcn_mfma_f32_16x16x32_bf16(pf1, vf1, oacc[t], 0, 0, 0);
            }
        }
    }

    float invl[4];
    #pragma unroll
    for (int r = 0; r < 4; ++r) invl[r] = 1.0f / l_run[r];
    #pragma unroll
    for (int r = 0; r < 4; ++r) {
        const int qrow = qt * 128 + wave * 16 + quad * 4 + r;
        us* orow = ctx + (size_t)(b * T_SEQ + qrow) * D_MODEL + h * 64;
        #pragma unroll
        for (int t = 0; t < 4; ++t) orow[t * 16 + l15] = f2b(oacc[t][r] * invl[r]);
    }
}

// ---------------------------------------------------------------------------
extern "C" void kernel_launch(void* const* d_in, const int* in_sizes, int n_in,
                              void* d_out, int out_size, void* d_ws, size_t ws_size,
                              hipStream_t stream)
{
    const float* x    = (const float*)d_in[0];
    const int*   idxp = (const int*)d_in[3];
    const float* Wq   = (const float*)d_in[4];
    const float* bq   = (const float*)d_in[5];
    const float* Wk   = (const float*)d_in[6];
    const float* bk   = (const float*)d_in[7];
    const float* Wv   = (const float*)d_in[8];
    const float* bv   = (const float*)d_in[9];
    const float* Wo   = (const float*)d_in[10];
    const float* bo   = (const float*)d_in[11];

    float* out      = (float*)d_out;
    us*    xb       = (us*)d_out;                                   // [0,16MB)
    us*    qb       = (us*)d_out + (size_t)8 * 1024 * 1024;         // [16,32MB)
    float* cacheOut = out + (size_t)4 * T_SEQ * D_MODEL;            // [32,96MB)

    us* WT3  = (us*)d_ws;                                           // [0,24MB)
    us* WTo  = (us*)d_ws;                                           // [0,8MB)  (after QKV)
    us* ctxb = (us*)d_ws + (size_t)4 * 1024 * 1024;                 // [8,24MB)

    const dim3 tb(256);

    cvtx_kernel<<<dim3(4096), tb, 0, stream>>>(x, xb);
    wtrans_kernel<<<dim3(32, 32, 3), tb, 0, stream>>>(Wq, Wk, Wv, WT3);

    // fused QKV: N = 6144 -> 48 x 32 = 1536 blocks (1536 % 8 == 0)
    gemm128_kernel<3><<<dim3(48, 32), tb, 0, stream>>>(
        xb, WT3, bq, bk, bv, (float*)qb, cacheOut, idxp);

    wtrans_kernel<<<dim3(32, 32, 1), tb, 0, stream>>>(Wo, Wo, Wo, WTo);

    attn_mfma_kernel<<<dim3(128, 8), dim3(512), 0, stream>>>(qb, cacheOut, ctxb);

    // O GEMM: N = 2048 -> 16 x 32 = 512 blocks (512 % 8 == 0)
    gemm128_kernel<0><<<dim3(16, 32), tb, 0, stream>>>(
        ctxb, WTo, bo, nullptr, nullptr, out, nullptr, nullptr);
}